// Round 1
// baseline (224.797 us; speedup 1.0000x reference)
//
#include <hip/hip_runtime.h>

// cov = R * diag(s^2) * R^T  per gaussian (COLMAP quat convention, no normalize).
// Memory-bound: 28 B in + 36 B out per gaussian. LDS-staged output for
// fully-coalesced dword store sweeps.

__global__ __launch_bounds__(256) void gaussian_cov_kernel(
    const float4* __restrict__ quat,   // [N] as (w,x,y,z)
    const float*  __restrict__ scales, // [N*3]
    float*        __restrict__ out,    // [N*9]
    int N) {
    __shared__ float lds[256 * 9];

    const int t = threadIdx.x;
    const int i = blockIdx.x * 256 + t;

    if (i < N) {
        const float4 q = quat[i];
        const float w = q.x, x = q.y, y = q.z, z = q.w;
        const float sx = scales[3 * i + 0];
        const float sy = scales[3 * i + 1];
        const float sz = scales[3 * i + 2];

        const float xx = 2.0f * x * x, yy = 2.0f * y * y, zz = 2.0f * z * z;
        const float xy = 2.0f * x * y, xz = 2.0f * x * z, yz = 2.0f * y * z;
        const float wx = 2.0f * w * x, wy = 2.0f * w * y, wz = 2.0f * w * z;

        const float R00 = 1.0f - yy - zz, R01 = xy - wz, R02 = xz + wy;
        const float R10 = xy + wz, R11 = 1.0f - xx - zz, R12 = yz - wx;
        const float R20 = xz - wy, R21 = yz + wx, R22 = 1.0f - xx - yy;

        const float s2x = sx * sx, s2y = sy * sy, s2z = sz * sz;

        // cov[i][j] = sum_k R[i][k]*R[j][k]*s2[k]  (symmetric)
        const float c00 = R00 * R00 * s2x + R01 * R01 * s2y + R02 * R02 * s2z;
        const float c01 = R00 * R10 * s2x + R01 * R11 * s2y + R02 * R12 * s2z;
        const float c02 = R00 * R20 * s2x + R01 * R21 * s2y + R02 * R22 * s2z;
        const float c11 = R10 * R10 * s2x + R11 * R11 * s2y + R12 * R12 * s2z;
        const float c12 = R10 * R20 * s2x + R11 * R21 * s2y + R12 * R22 * s2z;
        const float c22 = R20 * R20 * s2x + R21 * R21 * s2y + R22 * R22 * s2z;

        float* l = &lds[t * 9];
        l[0] = c00; l[1] = c01; l[2] = c02;
        l[3] = c01; l[4] = c11; l[5] = c12;
        l[6] = c02; l[7] = c12; l[8] = c22;
    }

    __syncthreads();

    // Coalesced sweep: block's output chunk is [base, base + 2304).
    const int base = blockIdx.x * (256 * 9);
    const int total = N * 9;
#pragma unroll
    for (int r = 0; r < 9; ++r) {
        const int idx = r * 256 + t;
        if (base + idx < total) {
            out[base + idx] = lds[idx];
        }
    }
}

extern "C" void kernel_launch(void* const* d_in, const int* in_sizes, int n_in,
                              void* d_out, int out_size, void* d_ws, size_t ws_size,
                              hipStream_t stream) {
    const float4* quat   = (const float4*)d_in[0];
    const float*  scales = (const float*)d_in[1];
    float*        out    = (float*)d_out;
    const int N = in_sizes[0] / 4;
    const int blocks = (N + 255) / 256;
    gaussian_cov_kernel<<<blocks, 256, 0, stream>>>(quat, scales, out, N);
}